// Round 1
// baseline (2330.023 us; speedup 1.0000x reference)
//
#include <hip/hip_runtime.h>
#include <math.h>

#define NN 10000
#define EE 320000

constexpr float INVS32  = 0.17677669529663687f;   // 1/sqrt(32)
constexpr float INVS160 = 0.07905694150420949f;   // 1/sqrt(160)
constexpr float INVS96  = 0.10206207261596575f;   // 1/sqrt(96)
constexpr float INVS3   = 0.5773502691896258f;    // 1/sqrt(3)
constexpr float INVS2   = 0.7071067811865476f;    // 1/sqrt(2)
constexpr float LN2     = 0.6931471805599453f;

__device__ __forceinline__ float sspf(float v) {
  // softplus(v) - log(2), numerically stable
  return fmaxf(v, 0.f) + log1pf(expf(-fabsf(v))) - LN2;
}

// ---------------- sort-by-dst kernels ----------------
__global__ void hist_k(const int* __restrict__ ei, int* __restrict__ cnt) {
  int e = blockIdx.x * 256 + threadIdx.x;
  if (e < EE) atomicAdd(&cnt[ei[e]], 1);
}

__global__ __launch_bounds__(1024) void scan_k(const int* __restrict__ cnt,
                                               int* __restrict__ offv,
                                               int* __restrict__ cursor) {
  __shared__ int s[1024];
  const int t = threadIdx.x;
  int loc[10];
  int sum = 0;
#pragma unroll
  for (int jj = 0; jj < 10; ++jj) {
    int idx = t * 10 + jj;
    int c = (idx < NN) ? cnt[idx] : 0;
    loc[jj] = sum;
    sum += c;
  }
  s[t] = sum;
  __syncthreads();
  for (int d = 1; d < 1024; d <<= 1) {
    int v = (t >= d) ? s[t - d] : 0;
    __syncthreads();
    s[t] += v;
    __syncthreads();
  }
  const int excl = (t > 0) ? s[t - 1] : 0;
#pragma unroll
  for (int jj = 0; jj < 10; ++jj) {
    int idx = t * 10 + jj;
    if (idx < NN) {
      offv[idx]   = excl + loc[jj];
      cursor[idx] = excl + loc[jj];
    }
  }
  if (t == 0) offv[NN] = EE;
}

__global__ void scat_k(const int* __restrict__ ei, int* __restrict__ cursor,
                       int* __restrict__ order) {
  int e = blockIdx.x * 256 + threadIdx.x;
  if (e < EE) {
    int p = atomicAdd(&cursor[ei[e]], 1);
    order[p] = e;
  }
}

// ---------------- node-level precompute ----------------
// per node: p1 (96), x0n (64), x1n (96), A (32), B (32)
__global__ __launch_bounds__(256) void node_prep_k(
    const float* __restrict__ x,
    const float* __restrict__ W0p, const float* __restrict__ b0p,
    const float* __restrict__ W1p,
    const float* __restrict__ W0n, const float* __restrict__ b0n,
    const float* __restrict__ W1n,
    const float* __restrict__ G1, const float* __restrict__ g1b,
    const float* __restrict__ G2, const float* __restrict__ g2b,
    const float* __restrict__ L1,
    float* __restrict__ p1w, float* __restrict__ x0nw, float* __restrict__ x1nw,
    float* __restrict__ Aw, float* __restrict__ Bw)
{
  const int wv   = threadIdx.x >> 6;
  const int lane = threadIdx.x & 63;
  const int n    = blockIdx.x * 4 + wv;
  const bool nv  = (n < NN);

  __shared__ float sX[4][160];
  __shared__ float sP0[4][64];
  __shared__ float sF0[4][96];
  __shared__ float sH1[4][96];
  __shared__ float sG[4][96];

  if (nv) {
    sX[wv][lane]      = x[n * 160 + lane];
    sX[wv][lane + 64] = x[n * 160 + lane + 64];
    if (lane < 32) sX[wv][lane + 128] = x[n * 160 + lane + 128];
  }
  __syncthreads();

  if (nv) {
    { // p0[o], o = lane < 64 ; also f0 low half
      float d = 0.f;
      for (int i = 0; i < 64; ++i) d += sX[wv][i] * W0p[i * 64 + lane];
      sP0[wv][lane] = d * 0.125f + b0p[lane];
      sF0[wv][lane] = sX[wv][lane];
    }
    // p1[v*3+i] = sum_u x1[u,i]*W1p[u,v]/sqrt(32)
    for (int o = lane; o < 96; o += 64) {
      const int v = o / 3, i_ = o % 3;
      float d = 0.f;
      for (int u = 0; u < 32; ++u) d += sX[wv][64 + u * 3 + i_] * W1p[u * 32 + v];
      p1w[n * 96 + o] = d * INVS32;
    }
    // n1
    if (lane < 32) {
      float s2 = 1e-12f;
#pragma unroll
      for (int i = 0; i < 3; ++i) { float t = sX[wv][64 + lane * 3 + i]; s2 += t * t; }
      sF0[wv][64 + lane] = sqrtf(s2);
    }
  }
  __syncthreads();

  if (nv) for (int o = lane; o < 96; o += 64) {
    float d = g1b[o];
    for (int i = 0; i < 96; ++i) d += sF0[wv][i] * G1[i * 96 + o];
    sH1[wv][o] = d / (1.f + expf(-d));   // silu
  }
  __syncthreads();

  if (nv) for (int o = lane; o < 96; o += 64) {
    float d = g2b[o];
    for (int i = 0; i < 96; ++i) d += sH1[wv][i] * G2[i * 96 + o];
    sG[wv][o] = d;
  }
  __syncthreads();

  if (nv) {
    { // x0n = g[:64] @ W0n/8 + b0n
      float d = 0.f;
      for (int i = 0; i < 64; ++i) d += sG[wv][i] * W0n[i * 64 + lane];
      x0nw[n * 64 + lane] = d * 0.125f + b0n[lane];
    }
    // x1n[v*3+i] = sum_u x1[u,i]*g[64+u]*W1n[u,v]/sqrt(32)
    for (int o = lane; o < 96; o += 64) {
      const int v = o / 3, i_ = o % 3;
      float d = 0.f;
      for (int u = 0; u < 32; ++u)
        d += sX[wv][64 + u * 3 + i_] * sG[wv][64 + u] * W1n[u * 32 + v];
      x1nw[n * 96 + o] = d * INVS32;
    }
    // A = p0 @ L1[0:64]/sqrt(160), B = p0 @ L1[64:128]/sqrt(160)
    if (lane < 32) {
      float a = 0.f, b = 0.f;
      for (int i = 0; i < 64; ++i) {
        a += sP0[wv][i] * L1[i * 32 + lane];
        b += sP0[wv][i] * L1[(64 + i) * 32 + lane];
      }
      Aw[n * 32 + lane] = a * INVS160;
      Bw[n * 32 + lane] = b * INVS160;
    }
  }
}

// ---------------- main fused edge+scatter+output kernel ----------------
// one block (256 thr) per dst node; processes its edge list in tiles of 16;
// accumulator for out480 lives in registers (k = tid, tid+256); fused WO matmuls.
__global__ __launch_bounds__(256) void edge_main_k(
    const float* __restrict__ edge_sh,
    const float* __restrict__ edge_attr,
    const int*   __restrict__ ei,
    const float* __restrict__ F1, const float* __restrict__ F2,
    const float* __restrict__ L1, const float* __restrict__ L2,
    const float* __restrict__ WO0, const float* __restrict__ bO0,
    const float* __restrict__ WO1, const float* __restrict__ WO2,
    const float* __restrict__ p1w, const float* __restrict__ x0nw,
    const float* __restrict__ x1nw, const float* __restrict__ Aw,
    const float* __restrict__ Bw,
    const int* __restrict__ offv, const int* __restrict__ order,
    float* __restrict__ out)
{
  const int n   = blockIdx.x;
  const int tid = threadIdx.x;
  const int g   = tid >> 4;   // edge slot 0..15
  const int j   = tid & 15;   // lane within edge group

  __shared__ float sP1d[96];
  __shared__ float sAd[32];
  __shared__ float sHF[16][32];
  __shared__ float sHL[16][32];
  __shared__ float sIP[16][32];
  __shared__ float sEA[16][32];
  __shared__ float sXS0[16][64];
  __shared__ float sXS1[16][96];
  __shared__ float sSH[16][4];
  __shared__ float sW[16][224];
  __shared__ float sOut[480];

  if (tid < 96) sP1d[tid] = p1w[n * 96 + tid];
  if (tid < 32) sAd[tid]  = Aw[n * 32 + tid];

  float acc0 = 0.f, acc1 = 0.f;
  const int e0 = offv[n];
  const int e1 = offv[n + 1];
  const int ntiles = (e1 - e0 + 15) >> 4;

  for (int tile = 0; tile < ntiles; ++tile) {
    __syncthreads();  // protect sP1d/sAd on first iter; LDS reuse across tiles
    const int idx    = e0 + (tile << 4) + g;
    const bool valid = (idx < e1);
    const int e      = order[valid ? idx : e0];
    const int srcn   = ei[EE + e];

    // ---- stage per-edge data ----
    sEA[g][j]      = edge_attr[e * 32 + j];
    sEA[g][j + 16] = edge_attr[e * 32 + j + 16];
#pragma unroll
    for (int m = 0; m < 4; ++m) sXS0[g][j + 16 * m] = x0nw[srcn * 64 + j + 16 * m];
#pragma unroll
    for (int m = 0; m < 6; ++m) sXS1[g][j + 16 * m] = x1nw[srcn * 96 + j + 16 * m];
    if (j < 4) sSH[g][j] = edge_sh[e * 4 + j];

    // ip1[v] = sum_i p1[dst][v,i]*p1[src][v,i]/sqrt(3)
#pragma unroll
    for (int vv = 0; vv < 2; ++vv) {
      const int v = j + 16 * vv;
      float s = 0.f;
#pragma unroll
      for (int i = 0; i < 3; ++i)
        s += sP1d[v * 3 + i] * p1w[srcn * 96 + v * 3 + i];
      sIP[g][v] = s * INVS3;
    }
    __syncthreads();

    // ---- hidden layers: t = A[dst]+B[src]+ip1@L1c ; u = ea@F1 ----
#pragma unroll
    for (int vv = 0; vv < 2; ++vv) {
      const int v = j + 16 * vv;
      float tacc = 0.f, uacc = 0.f;
      for (int c = 0; c < 32; ++c) {
        tacc += sIP[g][c] * L1[(128 + c) * 32 + v];
        uacc += sEA[g][c] * F1[c * 32 + v];
      }
      const float tv = sAd[v] + Bw[srcn * 32 + v] + tacc * INVS160;
      const float uv = uacc * INVS32;
      sHL[g][v] = valid ? sspf(tv) : 0.f;
      sHF[g][v] = valid ? sspf(uv) : 0.f;
    }
    __syncthreads();

    // ---- w[e][c] = (hf@F2)*(hl@L2)/32 ; thread c handles all 16 edges ----
    if (tid < 224) {
      const int c = tid;
      float aF[16], aL[16];
#pragma unroll
      for (int q = 0; q < 16; ++q) { aF[q] = 0.f; aL[q] = 0.f; }
      for (int i = 0; i < 32; ++i) {
        const float f2 = F2[i * 224 + c];
        const float l2 = L2[i * 224 + c];
#pragma unroll
        for (int q = 0; q < 16; ++q) {
          aF[q] = fmaf(sHF[q][i], f2, aF[q]);
          aL[q] = fmaf(sHL[q][i], l2, aL[q]);
        }
      }
#pragma unroll
      for (int q = 0; q < 16; ++q)
        sW[q][c] = aF[q] * aL[q] * (INVS32 * INVS32);
    }
    __syncthreads();

    // ---- accumulate 480-channel output in registers (no atomics) ----
    auto tile_acc = [&](int k) -> float {
      float a = 0.f;
      if (k < 64) {                       // o0a
        const int c = k;
#pragma unroll
        for (int q = 0; q < 16; ++q)
          a += sW[q][c] * sXS0[q][c] * sSH[q][0];
      } else if (k < 96) {                // o0b
        const int c = k - 64;
#pragma unroll
        for (int q = 0; q < 16; ++q) {
          float d = sXS1[q][c * 3 + 0] * sSH[q][1]
                  + sXS1[q][c * 3 + 1] * sSH[q][2]
                  + sXS1[q][c * 3 + 2] * sSH[q][3];
          a += sW[q][160 + c] * d * INVS3;
        }
      } else if (k < 288) {               // o1a
        const int qq = k - 96; const int u = qq / 3; const int i = qq - 3 * u;
#pragma unroll
        for (int q = 0; q < 16; ++q)
          a += sW[q][64 + u] * sXS0[q][u] * sSH[q][1 + i] * INVS3;
      } else if (k < 384) {               // o1b
        const int qq = k - 288; const int u = qq / 3; const int i = qq - 3 * u;
#pragma unroll
        for (int q = 0; q < 16; ++q)
          a += sW[q][128 + u] * sXS1[q][u * 3 + i] * sSH[q][0];
      } else {                            // o1c (cross product)
        const int qq = k - 384; const int u = qq / 3; const int i = qq - 3 * u;
        const int i1 = (i + 1) % 3, i2 = (i + 2) % 3;
#pragma unroll
        for (int q = 0; q < 16; ++q) {
          float cr = sXS1[q][u * 3 + i1] * sSH[q][1 + i2]
                   - sXS1[q][u * 3 + i2] * sSH[q][1 + i1];
          a += sW[q][192 + u] * cr * INVS2;
        }
      }
      return a;
    };
    acc0 += tile_acc(tid);
    if (tid < 224) acc1 += tile_acc(tid + 256);
  }

  // ---- fused output linears ----
  __syncthreads();
  sOut[tid] = acc0;
  if (tid < 224) sOut[tid + 256] = acc1;
  __syncthreads();

  for (int k = tid; k < 416; k += 256) {
    float y;
    if (k < 128) {
      float s = 0.f;
      for (int i = 0; i < 96; ++i) s += sOut[i] * WO0[i * 128 + k];
      y = s * INVS96 + bO0[k];
    } else if (k < 320) {
      const int qq = k - 128; const int v = qq / 3; const int i = qq - 3 * v;
      float s = 0.f;
      for (int u = 0; u < 96; ++u) s += sOut[96 + u * 3 + i] * WO1[u * 64 + v];
      y = s * INVS96;
    } else {
      const int qq = k - 320; const int v = qq / 3; const int i = qq - 3 * v;
      float s = 0.f;
      for (int u = 0; u < 32; ++u) s += sOut[384 + u * 3 + i] * WO2[u * 32 + v];
      y = s * INVS32;
    }
    out[n * 416 + k] = y;
  }
}

// ---------------- host ----------------
extern "C" void kernel_launch(void* const* d_in, const int* in_sizes, int n_in,
                              void* d_out, int out_size, void* d_ws, size_t ws_size,
                              hipStream_t stream) {
  const float* x         = (const float*)d_in[0];
  const float* edge_sh   = (const float*)d_in[1];
  const float* edge_attr = (const float*)d_in[2];
  const float* W0p       = (const float*)d_in[3];
  const float* b0p       = (const float*)d_in[4];
  const float* W1p       = (const float*)d_in[5];
  const float* W0n       = (const float*)d_in[6];
  const float* b0n       = (const float*)d_in[7];
  const float* W1n       = (const float*)d_in[8];
  const float* G1        = (const float*)d_in[9];
  const float* g1b       = (const float*)d_in[10];
  const float* G2        = (const float*)d_in[11];
  const float* g2b       = (const float*)d_in[12];
  const float* F1        = (const float*)d_in[13];
  const float* F2        = (const float*)d_in[14];
  const float* L1        = (const float*)d_in[15];
  const float* L2        = (const float*)d_in[16];
  const float* WO0       = (const float*)d_in[17];
  const float* bO0       = (const float*)d_in[18];
  const float* WO1       = (const float*)d_in[19];
  const float* WO2       = (const float*)d_in[20];
  const int*   ei        = (const int*)d_in[21];
  float* out = (float*)d_out;

  float* p1w  = (float*)d_ws;          // N*96
  float* x0nw = p1w  + NN * 96;        // N*64
  float* x1nw = x0nw + NN * 64;        // N*96
  float* Aw   = x1nw + NN * 96;        // N*32
  float* Bw   = Aw   + NN * 32;        // N*32
  int* cnt    = (int*)(Bw + NN * 32);  // N
  int* offv   = cnt    + NN;           // N+1
  int* cursor = offv   + NN + 1;       // N
  int* order  = cursor + NN;           // E

  hipMemsetAsync(cnt, 0, NN * sizeof(int), stream);
  hist_k<<<(EE + 255) / 256, 256, 0, stream>>>(ei, cnt);
  scan_k<<<1, 1024, 0, stream>>>(cnt, offv, cursor);
  scat_k<<<(EE + 255) / 256, 256, 0, stream>>>(ei, cursor, order);
  node_prep_k<<<(NN + 3) / 4, 256, 0, stream>>>(x, W0p, b0p, W1p, W0n, b0n, W1n,
                                                G1, g1b, G2, g2b, L1,
                                                p1w, x0nw, x1nw, Aw, Bw);
  edge_main_k<<<NN, 256, 0, stream>>>(edge_sh, edge_attr, ei, F1, F2, L1, L2,
                                      WO0, bO0, WO1, WO2,
                                      p1w, x0nw, x1nw, Aw, Bw, offv, order, out);
}

// Round 2
// 813.805 us; speedup vs baseline: 2.8631x; 2.8631x over previous
//
#include <hip/hip_runtime.h>
#include <hip/hip_bf16.h>
#include <math.h>

#define NN 10000
#define EE 320000

constexpr float INVS32  = 0.17677669529663687f;   // 1/sqrt(32)
constexpr float INVS160 = 0.07905694150420949f;   // 1/sqrt(160)
constexpr float INVS96  = 0.10206207261596575f;   // 1/sqrt(96)
constexpr float INVS3   = 0.5773502691896258f;    // 1/sqrt(3)
constexpr float INVS2   = 0.7071067811865476f;    // 1/sqrt(2)
constexpr float LN2     = 0.6931471805599453f;

__device__ __forceinline__ float sspf(float v) {
  return fmaxf(v, 0.f) + log1pf(expf(-fabsf(v))) - LN2;
}

// ---------------- sort-by-dst kernels ----------------
__global__ void hist_k(const int* __restrict__ ei, int* __restrict__ cnt) {
  int e = blockIdx.x * 256 + threadIdx.x;
  if (e < EE) atomicAdd(&cnt[ei[e]], 1);
}

__global__ __launch_bounds__(1024) void scan_k(const int* __restrict__ cnt,
                                               int* __restrict__ offv,
                                               int* __restrict__ cursor) {
  __shared__ int s[1024];
  const int t = threadIdx.x;
  int loc[10];
  int sum = 0;
#pragma unroll
  for (int jj = 0; jj < 10; ++jj) {
    int idx = t * 10 + jj;
    int c = (idx < NN) ? cnt[idx] : 0;
    loc[jj] = sum;
    sum += c;
  }
  s[t] = sum;
  __syncthreads();
  for (int d = 1; d < 1024; d <<= 1) {
    int v = (t >= d) ? s[t - d] : 0;
    __syncthreads();
    s[t] += v;
    __syncthreads();
  }
  const int excl = (t > 0) ? s[t - 1] : 0;
#pragma unroll
  for (int jj = 0; jj < 10; ++jj) {
    int idx = t * 10 + jj;
    if (idx < NN) {
      offv[idx]   = excl + loc[jj];
      cursor[idx] = excl + loc[jj];
    }
  }
  if (t == 0) offv[NN] = EE;
}

__global__ void scat_k(const int* __restrict__ ei, int* __restrict__ cursor,
                       int* __restrict__ order) {
  int e = blockIdx.x * 256 + threadIdx.x;
  if (e < EE) {
    int p = atomicAdd(&cursor[ei[e]], 1);
    order[p] = e;
  }
}

// ---------------- node-level precompute ----------------
__global__ __launch_bounds__(256) void node_prep_k(
    const float* __restrict__ x,
    const float* __restrict__ W0p, const float* __restrict__ b0p,
    const float* __restrict__ W1p,
    const float* __restrict__ W0n, const float* __restrict__ b0n,
    const float* __restrict__ W1n,
    const float* __restrict__ G1, const float* __restrict__ g1b,
    const float* __restrict__ G2, const float* __restrict__ g2b,
    const float* __restrict__ L1,
    float* __restrict__ p1w, float* __restrict__ x0nw, float* __restrict__ x1nw,
    float* __restrict__ Aw, float* __restrict__ Bw)
{
  const int wv   = threadIdx.x >> 6;
  const int lane = threadIdx.x & 63;
  const int n    = blockIdx.x * 4 + wv;
  const bool nv  = (n < NN);

  __shared__ float sX[4][160];
  __shared__ float sP0[4][64];
  __shared__ float sF0[4][96];
  __shared__ float sH1[4][96];
  __shared__ float sG[4][96];

  if (nv) {
    sX[wv][lane]      = x[n * 160 + lane];
    sX[wv][lane + 64] = x[n * 160 + lane + 64];
    if (lane < 32) sX[wv][lane + 128] = x[n * 160 + lane + 128];
  }
  __syncthreads();

  if (nv) {
    {
      float d = 0.f;
      for (int i = 0; i < 64; ++i) d += sX[wv][i] * W0p[i * 64 + lane];
      sP0[wv][lane] = d * 0.125f + b0p[lane];
      sF0[wv][lane] = sX[wv][lane];
    }
    for (int o = lane; o < 96; o += 64) {
      const int v = o / 3, i_ = o % 3;
      float d = 0.f;
      for (int u = 0; u < 32; ++u) d += sX[wv][64 + u * 3 + i_] * W1p[u * 32 + v];
      p1w[n * 96 + o] = d * INVS32;
    }
    if (lane < 32) {
      float s2 = 1e-12f;
#pragma unroll
      for (int i = 0; i < 3; ++i) { float t = sX[wv][64 + lane * 3 + i]; s2 += t * t; }
      sF0[wv][64 + lane] = sqrtf(s2);
    }
  }
  __syncthreads();

  if (nv) for (int o = lane; o < 96; o += 64) {
    float d = g1b[o];
    for (int i = 0; i < 96; ++i) d += sF0[wv][i] * G1[i * 96 + o];
    sH1[wv][o] = d / (1.f + expf(-d));
  }
  __syncthreads();

  if (nv) for (int o = lane; o < 96; o += 64) {
    float d = g2b[o];
    for (int i = 0; i < 96; ++i) d += sH1[wv][i] * G2[i * 96 + o];
    sG[wv][o] = d;
  }
  __syncthreads();

  if (nv) {
    {
      float d = 0.f;
      for (int i = 0; i < 64; ++i) d += sG[wv][i] * W0n[i * 64 + lane];
      x0nw[n * 64 + lane] = d * 0.125f + b0n[lane];
    }
    for (int o = lane; o < 96; o += 64) {
      const int v = o / 3, i_ = o % 3;
      float d = 0.f;
      for (int u = 0; u < 32; ++u)
        d += sX[wv][64 + u * 3 + i_] * sG[wv][64 + u] * W1n[u * 32 + v];
      x1nw[n * 96 + o] = d * INVS32;
    }
    if (lane < 32) {
      float a = 0.f, b = 0.f;
      for (int i = 0; i < 64; ++i) {
        a += sP0[wv][i] * L1[i * 32 + lane];
        b += sP0[wv][i] * L1[(64 + i) * 32 + lane];
      }
      Aw[n * 32 + lane] = a * INVS160;
      Bw[n * 32 + lane] = b * INVS160;
    }
  }
}

// ---------------- dense per-edge weight kernel ----------------
// block = 256 threads, 64 edges (sorted order). Computes hf, hl, then
// w[s][224] = (hf@F2)*(hl@L2)/32 written as bf16 in SORTED order.
__global__ __launch_bounds__(256) void edge_w_k(
    const float* __restrict__ edge_attr,
    const int* __restrict__ ei,
    const float* __restrict__ F1, const float* __restrict__ L1,
    const float* __restrict__ F2, const float* __restrict__ L2,
    const float* __restrict__ p1w, const float* __restrict__ Aw,
    const float* __restrict__ Bw,
    const int* __restrict__ order,
    __hip_bfloat16* __restrict__ wout)
{
  const int s0  = blockIdx.x * 64;
  const int tid = threadIdx.x;

  __shared__ float sEA[64][36];   // stride 36: 16B-aligned float4, <=2-way banks
  __shared__ float sIP[64][36];
  __shared__ float sHF[64][36];
  __shared__ float sHL[64][36];
  __shared__ int   sDst[64], sSrc[64];

  // ---- phase A: stage ea, ip, dst/src ----
  {
    const int g = tid >> 2, l = tid & 3;
    const int s = s0 + g;
    const int e = order[s];
    const int dst = ei[e], src = ei[EE + e];
    if (l == 0) { sDst[g] = dst; sSrc[g] = src; }

    const float4* ea4 = (const float4*)(edge_attr + (size_t)e * 32 + l * 8);
    *(float4*)&sEA[g][l * 8]     = ea4[0];
    *(float4*)&sEA[g][l * 8 + 4] = ea4[1];

    float dp[24], sp[24];
    const float4* pd = (const float4*)(p1w + (size_t)dst * 96 + l * 24);
    const float4* ps = (const float4*)(p1w + (size_t)src * 96 + l * 24);
#pragma unroll
    for (int k = 0; k < 6; ++k) {
      float4 v = pd[k]; dp[4*k] = v.x; dp[4*k+1] = v.y; dp[4*k+2] = v.z; dp[4*k+3] = v.w;
      float4 u = ps[k]; sp[4*k] = u.x; sp[4*k+1] = u.y; sp[4*k+2] = u.z; sp[4*k+3] = u.w;
    }
#pragma unroll
    for (int j = 0; j < 8; ++j) {
      const int b = 3 * j;
      sIP[g][l * 8 + j] =
        (dp[b] * sp[b] + dp[b+1] * sp[b+1] + dp[b+2] * sp[b+2]) * INVS3;
    }
  }
  __syncthreads();

  // ---- phase B: hidden layers ----
  {
    const int g = tid >> 2, l = tid & 3;
    const int dst = sDst[g], src = sSrc[g];
    float hfa[8], hla[8];
#pragma unroll
    for (int j = 0; j < 8; ++j) { hfa[j] = 0.f; hla[j] = 0.f; }
    for (int c = 0; c < 32; ++c) {
      const float eac = sEA[g][c];
      const float ipc = sIP[g][c];
      const float4* f14 = (const float4*)(F1 + c * 32 + l * 8);
      const float4* l14 = (const float4*)(L1 + (128 + c) * 32 + l * 8);
      float4 fA = f14[0], fB = f14[1], lA = l14[0], lB = l14[1];
      hfa[0] += eac * fA.x; hfa[1] += eac * fA.y; hfa[2] += eac * fA.z; hfa[3] += eac * fA.w;
      hfa[4] += eac * fB.x; hfa[5] += eac * fB.y; hfa[6] += eac * fB.z; hfa[7] += eac * fB.w;
      hla[0] += ipc * lA.x; hla[1] += ipc * lA.y; hla[2] += ipc * lA.z; hla[3] += ipc * lA.w;
      hla[4] += ipc * lB.x; hla[5] += ipc * lB.y; hla[6] += ipc * lB.z; hla[7] += ipc * lB.w;
    }
    const float4* av4 = (const float4*)(Aw + (size_t)dst * 32 + l * 8);
    const float4* bv4 = (const float4*)(Bw + (size_t)src * 32 + l * 8);
    float4 aA = av4[0], aB = av4[1], bA = bv4[0], bB = bv4[1];
    float av[8] = {aA.x, aA.y, aA.z, aA.w, aB.x, aB.y, aB.z, aB.w};
    float bv[8] = {bA.x, bA.y, bA.z, bA.w, bB.x, bB.y, bB.z, bB.w};
#pragma unroll
    for (int j = 0; j < 8; ++j) {
      sHF[g][l * 8 + j] = sspf(hfa[j] * INVS32);
      sHL[g][l * 8 + j] = sspf(av[j] + bv[j] + hla[j] * INVS160);
    }
  }
  __syncthreads();

  // ---- phase C: 224-wide double GEMM + multiply, 2 passes of 4 edges ----
  const int cl = tid & 31, eg = tid >> 5;
#pragma unroll 1
  for (int p = 0; p < 2; ++p) {
    const int gb = eg * 8 + p * 4;
    float aF[28], aL[28];
#pragma unroll
    for (int k = 0; k < 28; ++k) { aF[k] = 0.f; aL[k] = 0.f; }
    for (int i = 0; i < 32; ++i) {
      const float hf0 = sHF[gb + 0][i], hf1 = sHF[gb + 1][i];
      const float hf2 = sHF[gb + 2][i], hf3 = sHF[gb + 3][i];
      const float hl0 = sHL[gb + 0][i], hl1 = sHL[gb + 1][i];
      const float hl2 = sHL[gb + 2][i], hl3 = sHL[gb + 3][i];
#pragma unroll
      for (int cc = 0; cc < 7; ++cc) {
        const int c = cl + 32 * cc;
        const float f2  = F2[i * 224 + c];
        const float l2v = L2[i * 224 + c];
        aF[cc*4+0] = fmaf(hf0, f2, aF[cc*4+0]);
        aF[cc*4+1] = fmaf(hf1, f2, aF[cc*4+1]);
        aF[cc*4+2] = fmaf(hf2, f2, aF[cc*4+2]);
        aF[cc*4+3] = fmaf(hf3, f2, aF[cc*4+3]);
        aL[cc*4+0] = fmaf(hl0, l2v, aL[cc*4+0]);
        aL[cc*4+1] = fmaf(hl1, l2v, aL[cc*4+1]);
        aL[cc*4+2] = fmaf(hl2, l2v, aL[cc*4+2]);
        aL[cc*4+3] = fmaf(hl3, l2v, aL[cc*4+3]);
      }
    }
#pragma unroll
    for (int cc = 0; cc < 7; ++cc) {
      const int c = cl + 32 * cc;
#pragma unroll
      for (int q = 0; q < 4; ++q) {
        const float w = aF[cc*4+q] * aL[cc*4+q] * (1.0f / 32.0f);
        wout[(size_t)(s0 + gb + q) * 224 + c] = __float2bfloat16(w);
      }
    }
  }
}

// ---------------- per-dst-node scatter + fused output linears ----------------
__global__ __launch_bounds__(256) void node_out_k(
    const float* __restrict__ edge_sh,
    const int* __restrict__ ei,
    const float* __restrict__ WO0, const float* __restrict__ bO0,
    const float* __restrict__ WO1, const float* __restrict__ WO2,
    const float* __restrict__ x0nw, const float* __restrict__ x1nw,
    const __hip_bfloat16* __restrict__ wws,
    const int* __restrict__ offv, const int* __restrict__ order,
    float* __restrict__ out)
{
  const int n   = blockIdx.x;
  const int tid = threadIdx.x;

  __shared__ float sW[32 * 224];
  __shared__ float sXS0[32][64];
  __shared__ float sXS1[32][96];
  __shared__ float sSH[32][4];
  __shared__ float sOut[480];

  const int e0 = offv[n], e1 = offv[n + 1];
  float acc0 = 0.f, acc1 = 0.f;
  const int ntiles = (e1 - e0 + 31) >> 5;
  const int q = tid >> 3, l = tid & 7;

  auto chan = [&](int k) -> float {
    float a = 0.f;
    if (k < 64) {
      const int c = k;
#pragma unroll
      for (int qq = 0; qq < 32; ++qq)
        a += sW[qq * 224 + c] * sXS0[qq][c] * sSH[qq][0];
    } else if (k < 96) {
      const int c = k - 64;
#pragma unroll
      for (int qq = 0; qq < 32; ++qq) {
        float d = sXS1[qq][c*3+0] * sSH[qq][1]
                + sXS1[qq][c*3+1] * sSH[qq][2]
                + sXS1[qq][c*3+2] * sSH[qq][3];
        a += sW[qq * 224 + 160 + c] * d * INVS3;
      }
    } else if (k < 288) {
      const int kk = k - 96; const int u = kk / 3; const int i = kk - 3 * u;
#pragma unroll
      for (int qq = 0; qq < 32; ++qq)
        a += sW[qq * 224 + 64 + u] * sXS0[qq][u] * sSH[qq][1 + i] * INVS3;
    } else if (k < 384) {
      const int kk = k - 288; const int u = kk / 3; const int i = kk - 3 * u;
#pragma unroll
      for (int qq = 0; qq < 32; ++qq)
        a += sW[qq * 224 + 128 + u] * sXS1[qq][u * 3 + i] * sSH[qq][0];
    } else {
      const int kk = k - 384; const int u = kk / 3; const int i = kk - 3 * u;
      const int i1 = (i + 1) % 3, i2 = (i + 2) % 3;
#pragma unroll
      for (int qq = 0; qq < 32; ++qq) {
        float cr = sXS1[qq][u * 3 + i1] * sSH[qq][1 + i2]
                 - sXS1[qq][u * 3 + i2] * sSH[qq][1 + i1];
        a += sW[qq * 224 + 192 + u] * cr * INVS2;
      }
    }
    return a;
  };

  for (int t = 0; t < ntiles; ++t) {
    __syncthreads();
    const int idx    = e0 + t * 32 + q;
    const bool valid = (idx < e1);
    if (valid) {
      const int e    = order[idx];
      const int srcn = ei[EE + e];
      const ushort* wrow = (const ushort*)wws + (size_t)(e0 + t * 32) * 224 + tid * 28;
#pragma unroll
      for (int k = 0; k < 7; ++k) {
        ushort4 u = ((const ushort4*)wrow)[k];
        float4 f;
        f.x = __uint_as_float(((unsigned)u.x) << 16);
        f.y = __uint_as_float(((unsigned)u.y) << 16);
        f.z = __uint_as_float(((unsigned)u.z) << 16);
        f.w = __uint_as_float(((unsigned)u.w) << 16);
        *(float4*)&sW[tid * 28 + 4 * k] = f;
      }
      const float4* xs04 = (const float4*)(x0nw + (size_t)srcn * 64 + l * 8);
      *(float4*)&sXS0[q][l * 8]     = xs04[0];
      *(float4*)&sXS0[q][l * 8 + 4] = xs04[1];
      const float4* xs14 = (const float4*)(x1nw + (size_t)srcn * 96 + l * 12);
      *(float4*)&sXS1[q][l * 12]     = xs14[0];
      *(float4*)&sXS1[q][l * 12 + 4] = xs14[1];
      *(float4*)&sXS1[q][l * 12 + 8] = xs14[2];
      if (l == 0) *(float4*)&sSH[q][0] = *(const float4*)(edge_sh + (size_t)e * 4);
    } else {
      const float4 z = {0.f, 0.f, 0.f, 0.f};
#pragma unroll
      for (int k = 0; k < 7; ++k) *(float4*)&sW[tid * 28 + 4 * k] = z;
      *(float4*)&sXS0[q][l * 8]     = z;
      *(float4*)&sXS0[q][l * 8 + 4] = z;
      *(float4*)&sXS1[q][l * 12]     = z;
      *(float4*)&sXS1[q][l * 12 + 4] = z;
      *(float4*)&sXS1[q][l * 12 + 8] = z;
      if (l == 0) *(float4*)&sSH[q][0] = z;
    }
    __syncthreads();
    acc0 += chan(tid);
    if (tid < 224) acc1 += chan(tid + 256);
  }

  sOut[tid] = acc0;
  if (tid < 224) sOut[256 + tid] = acc1;
  __syncthreads();

  for (int k = tid; k < 416; k += 256) {
    float y;
    if (k < 128) {
      float s = 0.f;
      for (int i = 0; i < 96; ++i) s += sOut[i] * WO0[i * 128 + k];
      y = s * INVS96 + bO0[k];
    } else if (k < 320) {
      const int kk = k - 128; const int v = kk / 3; const int i = kk - 3 * v;
      float s = 0.f;
      for (int u = 0; u < 96; ++u) s += sOut[96 + u * 3 + i] * WO1[u * 64 + v];
      y = s * INVS96;
    } else {
      const int kk = k - 320; const int v = kk / 3; const int i = kk - 3 * v;
      float s = 0.f;
      for (int u = 0; u < 32; ++u) s += sOut[384 + u * 3 + i] * WO2[u * 32 + v];
      y = s * INVS32;
    }
    out[n * 416 + k] = y;
  }
}

// ---------------- host ----------------
extern "C" void kernel_launch(void* const* d_in, const int* in_sizes, int n_in,
                              void* d_out, int out_size, void* d_ws, size_t ws_size,
                              hipStream_t stream) {
  const float* x         = (const float*)d_in[0];
  const float* edge_sh   = (const float*)d_in[1];
  const float* edge_attr = (const float*)d_in[2];
  const float* W0p       = (const float*)d_in[3];
  const float* b0p       = (const float*)d_in[4];
  const float* W1p       = (const float*)d_in[5];
  const float* W0n       = (const float*)d_in[6];
  const float* b0n       = (const float*)d_in[7];
  const float* W1n       = (const float*)d_in[8];
  const float* G1        = (const float*)d_in[9];
  const float* g1b       = (const float*)d_in[10];
  const float* G2        = (const float*)d_in[11];
  const float* g2b       = (const float*)d_in[12];
  const float* F1        = (const float*)d_in[13];
  const float* F2        = (const float*)d_in[14];
  const float* L1        = (const float*)d_in[15];
  const float* L2        = (const float*)d_in[16];
  const float* WO0       = (const float*)d_in[17];
  const float* bO0       = (const float*)d_in[18];
  const float* WO1       = (const float*)d_in[19];
  const float* WO2       = (const float*)d_in[20];
  const int*   ei        = (const int*)d_in[21];
  float* out = (float*)d_out;

  float* p1w  = (float*)d_ws;          // N*96
  float* x0nw = p1w  + NN * 96;        // N*64
  float* x1nw = x0nw + NN * 64;        // N*96
  float* Aw   = x1nw + NN * 96;        // N*32
  float* Bw   = Aw   + NN * 32;        // N*32
  int* cnt    = (int*)(Bw + NN * 32);  // N
  int* offv   = cnt    + NN;           // N+1
  int* cursor = offv   + NN + 1;       // N
  int* order  = cursor + NN;           // E
  uintptr_t wp = (uintptr_t)(order + EE);
  wp = (wp + 15) & ~(uintptr_t)15;
  __hip_bfloat16* wws = (__hip_bfloat16*)wp;   // E*224 bf16 (~143 MB)

  hipMemsetAsync(cnt, 0, NN * sizeof(int), stream);
  hist_k<<<(EE + 255) / 256, 256, 0, stream>>>(ei, cnt);
  scan_k<<<1, 1024, 0, stream>>>(cnt, offv, cursor);
  scat_k<<<(EE + 255) / 256, 256, 0, stream>>>(ei, cursor, order);
  node_prep_k<<<(NN + 3) / 4, 256, 0, stream>>>(x, W0p, b0p, W1p, W0n, b0n, W1n,
                                                G1, g1b, G2, g2b, L1,
                                                p1w, x0nw, x1nw, Aw, Bw);
  edge_w_k<<<EE / 64, 256, 0, stream>>>(edge_attr, ei, F1, L1, F2, L2,
                                        p1w, Aw, Bw, order, wws);
  node_out_k<<<NN, 256, 0, stream>>>(edge_sh, ei, WO0, bO0, WO1, WO2,
                                     x0nw, x1nw, wws, offv, order, out);
}